// Round 15
// baseline (49.709 us; speedup 1.0000x reference)
//
#include <hip/hip_runtime.h>
#include <math.h>

typedef unsigned short u16;
typedef unsigned int u32;
typedef __attribute__((ext_vector_type(2))) float f32x2;
typedef __attribute__((ext_vector_type(4))) float f32x4;
typedef __attribute__((ext_vector_type(8))) short bf16x8;

// adjacency-collapse constants: u = 1/(6+1e-8); s = 1+6u; c1=1/s; c2=c1^2; a=u/s; a1c=a*(1+c1)
#define U_CONST   0.16666666638888889f
#define C1_CONST  0.5000000004166667f
#define C2_CONST  0.2500000004166667f
#define A_CONST   0.08333333326388889f
#define A1C_CONST 0.12499999993055555f

__device__ __forceinline__ float bf2f(u16 u){ union{u32 i; float f;} v; v.i=((u32)u)<<16; return v.f; }
__device__ __forceinline__ u16 f2bf(float f){ union{float f; u32 i;} v; v.f=f; u32 x=v.i;
  return (u16)((x + 0x7FFFu + ((x>>16)&1u)) >> 16); }  // RNE

// packed f32 pair -> 2xbf16 (RNE), one instr
__device__ __forceinline__ u32 cvtpk(float lo, float hi){
  u32 r; asm("v_cvt_pk_bf16_f32 %0, %1, %2" : "=v"(r) : "v"(lo), "v"(hi)); return r;
}

// DPP lane exchange on VALU pipe (no LDS). 16-lane sum butterfly.
template<int C> __device__ __forceinline__ float dpp_mov(float x){
  return __int_as_float(__builtin_amdgcn_update_dpp(0, __float_as_int(x), C, 0xF, 0xF, true));
}
__device__ __forceinline__ float dpp_sum16(float v){
  v += dpp_mov<0xB1>(v);
  v += dpp_mov<0x4E>(v);
  v += dpp_mov<0x141>(v);
  v += dpp_mov<0x140>(v);
  return v;
}

// tanh-form gelu: x*sigmoid(1.5957691(x+0.044715x^3)); |err vs exact erf-gelu| ~3e-4
__device__ __forceinline__ float gelu_f(float x){
  float x2 = x*x;
  float t  = x * fmaf(x2, 0.07135481283f, 1.595769122f);
  float e  = __expf(-t);
  return x * __builtin_amdgcn_rcpf(1.0f + e);
}
__device__ __forceinline__ float sigmoid_f(float z){
  return __builtin_amdgcn_rcpf(1.0f + __expf(-z));
}

__device__ __forceinline__ bf16x8 pack8(f32x4 a, f32x4 b){
  union { bf16x8 v; u32 w[4]; } r;
  r.w[0]=cvtpk(a[0],a[1]); r.w[1]=cvtpk(a[2],a[3]);
  r.w[2]=cvtpk(b[0],b[1]); r.w[3]=cvtpk(b[2],b[3]);
  return r.v;
}

// in-wave LayerNorm over 128 cols: lane holds col (n<<4)+cl, rows cq*4+j. DPP reduce.
template<bool GELU>
__device__ __forceinline__ void ln_rows(f32x4 (&acc)[8], const float* __restrict__ gvec,
                                        const float* __restrict__ bvec, int cl){
  float sm[4]={0,0,0,0}, sq[4]={0,0,0,0};
  #pragma unroll
  for (int n=0;n<8;n++)
    #pragma unroll
    for (int j=0;j<4;j++){ float x = acc[n][j]; sm[j]+=x; sq[j]+=x*x; }
  #pragma unroll
  for (int j=0;j<4;j++){
    sm[j] = dpp_sum16(sm[j]);
    sq[j] = dpp_sum16(sq[j]);
    float m = sm[j]*0.0078125f;
    float r = rsqrtf(sq[j]*0.0078125f - m*m + 1e-5f);
    sm[j]=m; sq[j]=r;
  }
  #pragma unroll
  for (int n=0;n<8;n++){
    float gg = gvec[(n<<4)+cl], be = bvec[(n<<4)+cl];
    #pragma unroll
    for (int j=0;j<4;j++){
      float y = (acc[n][j]-sm[j])*sq[j]*gg + be;
      acc[n][j] = GELU ? gelu_f(y) : y;
    }
  }
}

__device__ __forceinline__ void add_vec(f32x4 (&acc)[8], const float* __restrict__ v, int cl){
  #pragma unroll
  for (int n=0;n<8;n++){ float bv = v[(n<<4)+cl];
    #pragma unroll
    for (int j=0;j<4;j++) acc[n][j]+=bv; }
}

// wave-private group sums over rows (rows 0-5 -> s0, 6-11 -> s1), cross-cq shfl
__device__ __forceinline__ void gsum(const f32x4 (&acc)[8], float (&s0)[8], float (&s1)[8], int cq){
  #pragma unroll
  for (int n=0;n<8;n++){
    float a=0.f, b=0.f;
    #pragma unroll
    for (int j=0;j<4;j++){
      int row = (cq<<2)+j;
      float y = acc[n][j];
      a += (row<6)? y : 0.f;
      b += (row>=6 && row<12)? y : 0.f;
    }
    a += __shfl_xor(a,16); a += __shfl_xor(a,32);
    b += __shfl_xor(b,16); b += __shfl_xor(b,32);
    s0[n]=a; s1[n]=b;
  }
}

// store rows 0..11 to global f32 (non-temporal; outputs never re-read) + wave-private LDS A tile
__device__ __forceinline__ void spill(const f32x4 (&acc)[8], float* __restrict__ gdst,
                                      char* Al, int cl, int cq){
  #pragma unroll
  for (int n=0;n<8;n++)
    #pragma unroll
    for (int j=0;j<4;j++){
      int R=(cq<<2)+j;
      float y=acc[n][j];
      float yo=dpp_mov<0xB1>(y);                 // xor1 partner on VALU
      if (R<12 && !(cl&1)){
        int col=(n<<4)+cl;
        __builtin_nontemporal_store((f32x2){y,yo}, (f32x2*)(gdst + (size_t)R*128 + col));
        *(u32*)(Al + (R<<8) + ((col<<1) ^ ((R&7)<<4))) = cvtpk(y,yo);
      }
    }
}

// group sums -> wave-private S tile [2][128] bf16 (unswizzled; reads are broadcasts)
__device__ __forceinline__ void ssave(const f32x4 (&acc)[8], char* Sl, int cl, int cq){
  float s0[8], s1[8];
  gsum(acc, s0, s1, cq);
  #pragma unroll
  for (int n=0;n<8;n++){
    float a_ = dpp_mov<0xB1>(s0[n]), b_ = dpp_mov<0xB1>(s1[n]);
    if (cq==0 && !(cl&1)){
      int col=(n<<4)+cl;
      *(u32*)(Sl + (col<<1))       = cvtpk(s0[n], a_);
      *(u32*)(Sl + 256 + (col<<1)) = cvtpk(s1[n], b_);
    }
  }
}

// ---------- zero-VGPR W staging: global_load_lds, linear dest, pre-swizzled source ----------
// full slot: 32KB (512 thr x 4 x 16B)
__device__ __forceinline__ void stage_lds(u16* Wb, const u16* __restrict__ slot, int w, int lane){
  const char* g = (const char*)slot + (w<<12) + (lane<<4);
  char* l = (char*)Wb + (w<<12);
  #pragma unroll
  for (int i=0;i<4;i++)
    __builtin_amdgcn_global_load_lds(
      (const __attribute__((address_space(1))) u32*)(g + (i<<10)),
      (__attribute__((address_space(3))) u32*)(l + (i<<10)), 16, 0, 0);
}
// half slot: 16KB (512 thr x 2 x 16B), linear
__device__ __forceinline__ void stage_half(char* ldst, const char* __restrict__ gsrc, int w, int lane){
  int off = (w<<10) + (lane<<4);
  #pragma unroll
  for (int j=0;j<2;j++)
    __builtin_amdgcn_global_load_lds(
      (const __attribute__((address_space(1))) u32*)(gsrc + (j<<13) + off),
      (__attribute__((address_space(3))) u32*)(ldst + (j<<13) + off), 16, 0, 0);
}
// B-frag slot XOR now also mixes col bit-3 (^(col>>3&1)<<2): splits the {cl, cl+8} bank-alias
// pair into different bank groups -> 8-way aliasing becomes 4-way (m136: 2.94x -> 1.58x).
__device__ __forceinline__ bf16x8 bfrag(const u16* Wb, int col, int kt, int cq){
  int s = (kt<<2) + cq;
  int p = s ^ (col&7) ^ (((col>>3)&1)<<2);
  return *(const bf16x8*)((const char*)Wb + (col<<8) + (p<<4));
}
__device__ __forceinline__ bf16x8 afrag(const char* Al, int rl, int kt, int cq){
  return *(const bf16x8*)(Al + (rl<<8) + (((kt<<6)+(cq<<4)) ^ ((rl&7)<<4)));
}

// K=128 half-GEMM: A from wave-private Al tile, B from staged Wb. setprio(T5) around MFMA.
template<bool INIT>
__device__ __forceinline__ void gemm_a(const u16* Wb, const char* Al, int rl, int cl, int cq,
                                       f32x4 (&acc)[8]){
  if (INIT){
    #pragma unroll
    for (int n=0;n<8;n++) acc[n]=(f32x4){0,0,0,0};
  }
  __builtin_amdgcn_s_setprio(1);
  #pragma unroll
  for (int kt=0;kt<4;kt++){
    bf16x8 a = afrag(Al, rl, kt, cq);
    #pragma unroll
    for (int n=0;n<8;n++)
      acc[n] = __builtin_amdgcn_mfma_f32_16x16x32_bf16(a, bfrag(Wb,(n<<4)+cl,kt,cq), acc[n],0,0,0);
  }
  __builtin_amdgcn_s_setprio(0);
}
// gemm_s col-half: output cols [n0*16, n0*16+63], B from Wbase (Wc for h0, Wb for h1)
__device__ __forceinline__ void gemm_s_h(const u16* Wbase, const char* Sl, int grp,
                                         int cl, int cq, int n0, f32x4 (&acc)[8]){
  __builtin_amdgcn_s_setprio(1);
  #pragma unroll
  for (int kt=0;kt<4;kt++){
    bf16x8 a = *(const bf16x8*)(Sl + (grp<<8) + (kt<<6) + (cq<<4));
    #pragma unroll
    for (int n=0;n<4;n++)
      acc[n0+n] = __builtin_amdgcn_mfma_f32_16x16x32_bf16(a, bfrag(Wbase,((n0+n)<<4)+cl,kt,cq), acc[n0+n],0,0,0);
  }
  __builtin_amdgcn_s_setprio(0);
}

// ---------- prep: 5 bf16 W^T slots, stored as the LDS IMAGE (swizzle baked into source) ----------
// u16 idx within slot for W^T[h][f]: (h<<7) + (p<<3) + (f&7),
// p = (f>>3) ^ (h&7) ^ (((h>>3)&1)<<2)   (matches bfrag)
// slots: 0:W1T  16384:WxT  32768:WsvT  49152:sW1aT  65536:(u*sW1b)T
__global__ void k_prep(const float* __restrict__ W1, const float* __restrict__ chw,
                       const float* __restrict__ sW1, u16* __restrict__ WT5){
  int i = blockIdx.x*256 + threadIdx.x;          // i = f*128+h
  int f = i>>7, h = i&127;
  int p = (f>>3) ^ (h&7) ^ (((h>>3)&1)<<2);
  int dst = (h<<7) + (p<<3) + (f&7);
  float w0 = chw[i], w1 = chw[16384+i], w2 = chw[32768+i];
  WT5[dst]         = f2bf(W1[i]);
  WT5[16384+dst]   = f2bf(w0 + C1_CONST*w1 + C2_CONST*w2);
  WT5[32768+dst]   = f2bf(A_CONST*w1 + A1C_CONST*w2);
  WT5[49152+dst]   = f2bf(sW1[i]);
  WT5[65536+dst]   = f2bf(U_CONST*sW1[16384+i]);
}

// ---------- fused pipeline: 8 waves/block, wave = 2 groups (12 rows), 9 barriers,
//            zero exposed DMA (Wc slack buffer holds h0 of each gemm_s table) ----------
__global__ __launch_bounds__(512, 4)
void k_all(const float* __restrict__ X_de, const u16* __restrict__ WT5,
           const float* __restrict__ b1, const float* __restrict__ ln1g, const float* __restrict__ ln1b,
           const float* __restrict__ chb, const float* __restrict__ clng, const float* __restrict__ clnb,
           const float* __restrict__ sb1, const float* __restrict__ slng, const float* __restrict__ slnb,
           const float* __restrict__ sW2, const float* __restrict__ sb2p,
           float* __restrict__ out)
{
  __shared__ __align__(16) u16  Wb[128*128];     // 32KB main staged weight (swizzled image)
  __shared__ __align__(16) u16  Wc[64*128];      // 16KB gemm_s h0 table (cols 0-63)
  __shared__ __align__(16) char lds[8][3584];    // per wave: A tile 12x256B + S tile 512B
  const int tid=threadIdx.x, w=tid>>6, lane=tid&63, cl=lane&15, cq=lane>>4;
  char* Al = lds[w];
  char* Sl = lds[w] + 3072;
  const int wid = blockIdx.x*8 + w;
  const int R0 = wid*12, g0 = wid*2;
  const int rl = (cl<12)? cl : 0;
  const int grp = (rl>=6)? 1 : 0;

  // prologue DMAs: W1T (32KB -> Wb) and WsvT-h0 (16KB -> Wc), both in flight below
  stage_lds(Wb, WT5, w, lane);
  stage_half((char*)Wc, (const char*)(WT5+32768), w, lane);

  // adj output: constant (LN over size-1 axis == aln_b -> softmax uniform). 576/block.
  {
    float* adj = out + 1048576;
    #pragma unroll
    for (int k=0;k<2;k++){
      int idx = tid + (k<<9);
      if (idx < 576) __builtin_nontemporal_store(0.16666667f, adj + (size_t)blockIdx.x*576 + idx);
    }
  }

  // stage-1 A preload
  int grow = R0 + rl;
  u32 grp6 = ((u32)grow * 43691u) >> 18;         // grow/6 (exact in range)
  int c = grow - (int)grp6*6;
  const float* xrow = X_de + (((size_t)(((int)(grp6>>7))*6 + c)<<7) + (int)(grp6&127))*128 + (cq<<3);
  f32x4 xlo0 = *(const f32x4*)(xrow);
  f32x4 xhi0 = *(const f32x4*)(xrow+4);
  f32x4 xlo1 = *(const f32x4*)(xrow+32);
  f32x4 xhi1 = *(const f32x4*)(xrow+36);
  f32x4 xlo2 = *(const f32x4*)(xrow+64);
  f32x4 xhi2 = *(const f32x4*)(xrow+68);
  f32x4 xlo3 = *(const f32x4*)(xrow+96);
  f32x4 xhi3 = *(const f32x4*)(xrow+100);
  bf16x8 af0 = pack8(xlo0,xhi0), af1 = pack8(xlo1,xhi1), af2 = pack8(xlo2,xhi2), af3 = pack8(xlo3,xhi3);
  __syncthreads();                               // b0: Wb = W1T, Wc = Wsv-h0

  // ---- stage 1: Xn = gelu(LN(X@W1 + b1)) ----
  f32x4 acc[8];
  #pragma unroll
  for (int n=0;n<8;n++) acc[n]=(f32x4){0,0,0,0};
  __builtin_amdgcn_s_setprio(1);
  #pragma unroll
  for (int n=0;n<8;n++) acc[n]=__builtin_amdgcn_mfma_f32_16x16x32_bf16(af0, bfrag(Wb,(n<<4)+cl,0,cq), acc[n],0,0,0);
  #pragma unroll
  for (int n=0;n<8;n++) acc[n]=__builtin_amdgcn_mfma_f32_16x16x32_bf16(af1, bfrag(Wb,(n<<4)+cl,1,cq), acc[n],0,0,0);
  #pragma unroll
  for (int n=0;n<8;n++) acc[n]=__builtin_amdgcn_mfma_f32_16x16x32_bf16(af2, bfrag(Wb,(n<<4)+cl,2,cq), acc[n],0,0,0);
  #pragma unroll
  for (int n=0;n<8;n++) acc[n]=__builtin_amdgcn_mfma_f32_16x16x32_bf16(af3, bfrag(Wb,(n<<4)+cl,3,cq), acc[n],0,0,0);
  __builtin_amdgcn_s_setprio(0);
  __syncthreads();                               // b1: all waves done reading W1T
  stage_lds(Wb, WT5+16384, w, lane);             // WxT DMA (hides under epilogue)
  add_vec(acc, b1, cl);
  ln_rows<true>(acc, ln1g, ln1b, cl);
  spill(acc, out + 1343488 + (size_t)R0*128, Al, cl, cq);   // Xn + LDS chain
  ssave(acc, Sl, cl, cq);                                   // S
  __syncthreads();                               // b2: Wb = WxT

  // ---- stage 2: g = LN(Xn@Wx + S@Wsv + chb) ----
  gemm_a<true>(Wb, Al, rl, cl, cq, acc);
  __syncthreads();                               // b3: Wx reads done (Wb.h1 free)
  stage_half((char*)Wb + 16384, (const char*)(WT5+32768) + 16384, w, lane); // Wsv-h1 -> Wb.h1
  gemm_s_h(Wc, Sl, grp, cl, cq, 0, acc);         // S@Wsv cols 0-63 (hides the DMA)
  __syncthreads();                               // b4: Wsv-h1 ready in Wb.h1
  gemm_s_h(Wb, Sl, grp, cl, cq, 4, acc);         // S@Wsv cols 64-127
  __syncthreads();                               // b5: Wb + Wc free
  stage_lds(Wb, WT5+49152, w, lane);             // sW1aT DMA (hides under epilogue)
  stage_half((char*)Wc, (const char*)(WT5+65536), w, lane); // sW1b'-h0 -> Wc
  add_vec(acc, chb, cl);
  ln_rows<false>(acc, clng, clnb, cl);
  spill(acc, out + 7634944 + (size_t)R0*128, Al, cl, cq);   // g + LDS chain
  ssave(acc, Sl, cl, cq);                                   // Sg
  __syncthreads();                               // b6: Wb = sW1aT, Wc = sW1b'-h0

  // ---- stage 3: h = gelu(LN(g@sW1a + Sg@(u*sW1b) + sb1)); att; epoch ----
  gemm_a<true>(Wb, Al, rl, cl, cq, acc);
  __syncthreads();                               // b7: sW1a reads done
  stage_half((char*)Wb + 16384, (const char*)(WT5+65536) + 16384, w, lane); // sW1b'-h1
  gemm_s_h(Wc, Sl, grp, cl, cq, 0, acc);         // Sg@(u*sW1b) cols 0-63
  __syncthreads();                               // b8: h1 ready
  gemm_s_h(Wb, Sl, grp, cl, cq, 4, acc);         // cols 64-127
  add_vec(acc, sb1, cl);
  ln_rows<true>(acc, slng, slnb, cl);

  float z0=0,z1=0,z2=0,z3=0;
  #pragma unroll
  for (int n=0;n<8;n++){
    float wv = sW2[(n<<4)+cl];
    z0 = fmaf(acc[n][0], wv, z0); z1 = fmaf(acc[n][1], wv, z1);
    z2 = fmaf(acc[n][2], wv, z2); z3 = fmaf(acc[n][3], wv, z3);
  }
  z0 = dpp_sum16(z0); z1 = dpp_sum16(z1); z2 = dpp_sum16(z2); z3 = dpp_sum16(z3);
  float s2 = sb2p[0];
  float a0 = sigmoid_f(z0+s2), a1 = sigmoid_f(z1+s2), a2 = sigmoid_f(z2+s2), a3 = sigmoid_f(z3+s2);

  float attr[12];
  #pragma unroll
  for (int r=0;r<12;r++){
    int src = (r>>2)<<4;
    float v = (r&3)==0 ? a0 : (r&3)==1 ? a1 : (r&3)==2 ? a2 : a3;
    attr[r] = __shfl(v, src);
  }
  // epoch: weighted mean over 6 node rows, g read from wave-private LDS (bf16)
  const int c2 = lane<<1;
  #pragma unroll
  for (int gi=0; gi<2; ++gi){
    float ex=0.f, ey=0.f;
    #pragma unroll
    for (int i=0;i<6;i++){
      int r = gi*6+i;
      u32 p = *(const u32*)(Al + (r<<8) + ((c2<<1) ^ ((r&7)<<4)));
      ex = fmaf(attr[r], bf2f((u16)(p&0xFFFFu)), ex);
      ey = fmaf(attr[r], bf2f((u16)(p>>16)), ey);
    }
    __builtin_nontemporal_store((f32x2){ex*(1.0f/6.0f), ey*(1.0f/6.0f)},
                                (f32x2*)(out + (size_t)(g0+gi)*128 + c2));
  }
}

// ---------- launcher ----------
extern "C" void kernel_launch(void* const* d_in, const int* in_sizes, int n_in,
                              void* d_out, int out_size, void* d_ws, size_t ws_size,
                              hipStream_t stream){
  const float* X_de = (const float*)d_in[0];
  const float* W1   = (const float*)d_in[1];
  const float* b1   = (const float*)d_in[2];
  const float* ln1g = (const float*)d_in[3];
  const float* ln1b = (const float*)d_in[4];
  // d_in[5..8] (aw, ab, aln_g, aln_b) mathematically dead: LN over size-1 axis == aln_b
  const float* chw  = (const float*)d_in[9];
  const float* chb  = (const float*)d_in[10];
  const float* clng = (const float*)d_in[11];
  const float* clnb = (const float*)d_in[12];
  const float* sW1  = (const float*)d_in[13];
  const float* sb1  = (const float*)d_in[14];
  const float* slng = (const float*)d_in[15];
  const float* slnb = (const float*)d_in[16];
  const float* sW2  = (const float*)d_in[17];
  const float* sb2  = (const float*)d_in[18];

  float* out = (float*)d_out;
  u16* WT5 = (u16*)d_ws;   // 160KB: 5 x 32KB bf16 W^T slots (LDS-image layout)

  hipLaunchKernelGGL(k_prep, dim3(64),  dim3(256), 0, stream, W1, chw, sW1, WT5);
  hipLaunchKernelGGL(k_all,  dim3(512), dim3(512), 0, stream,
                     X_de, WT5, b1, ln1g, ln1b, chb, clng, clnb,
                     sb1, slng, slnb, sW2, sb2, out);
}

// Round 16
// 45.674 us; speedup vs baseline: 1.0883x; 1.0883x over previous
//
#include <hip/hip_runtime.h>
#include <math.h>

typedef unsigned short u16;
typedef unsigned int u32;
typedef __attribute__((ext_vector_type(2))) float f32x2;
typedef __attribute__((ext_vector_type(4))) float f32x4;
typedef __attribute__((ext_vector_type(8))) short bf16x8;

// adjacency-collapse constants: u = 1/(6+1e-8); s = 1+6u; c1=1/s; c2=c1^2; a=u/s; a1c=a*(1+c1)
#define U_CONST   0.16666666638888889f
#define C1_CONST  0.5000000004166667f
#define C2_CONST  0.2500000004166667f
#define A_CONST   0.08333333326388889f
#define A1C_CONST 0.12499999993055555f

__device__ __forceinline__ float bf2f(u16 u){ union{u32 i; float f;} v; v.i=((u32)u)<<16; return v.f; }
__device__ __forceinline__ u16 f2bf(float f){ union{float f; u32 i;} v; v.f=f; u32 x=v.i;
  return (u16)((x + 0x7FFFu + ((x>>16)&1u)) >> 16); }  // RNE

// packed f32 pair -> 2xbf16 (RNE), one instr
__device__ __forceinline__ u32 cvtpk(float lo, float hi){
  u32 r; asm("v_cvt_pk_bf16_f32 %0, %1, %2" : "=v"(r) : "v"(lo), "v"(hi)); return r;
}

// DPP lane exchange on VALU pipe (no LDS). 16-lane sum butterfly.
template<int C> __device__ __forceinline__ float dpp_mov(float x){
  return __int_as_float(__builtin_amdgcn_update_dpp(0, __float_as_int(x), C, 0xF, 0xF, true));
}
__device__ __forceinline__ float dpp_sum16(float v){
  v += dpp_mov<0xB1>(v);
  v += dpp_mov<0x4E>(v);
  v += dpp_mov<0x141>(v);
  v += dpp_mov<0x140>(v);
  return v;
}

// tanh-form gelu: x*sigmoid(1.5957691(x+0.044715x^3)); |err vs exact erf-gelu| ~3e-4
__device__ __forceinline__ float gelu_f(float x){
  float x2 = x*x;
  float t  = x * fmaf(x2, 0.07135481283f, 1.595769122f);
  float e  = __expf(-t);
  return x * __builtin_amdgcn_rcpf(1.0f + e);
}
__device__ __forceinline__ float sigmoid_f(float z){
  return __builtin_amdgcn_rcpf(1.0f + __expf(-z));
}

__device__ __forceinline__ bf16x8 pack8(f32x4 a, f32x4 b){
  union { bf16x8 v; u32 w[4]; } r;
  r.w[0]=cvtpk(a[0],a[1]); r.w[1]=cvtpk(a[2],a[3]);
  r.w[2]=cvtpk(b[0],b[1]); r.w[3]=cvtpk(b[2],b[3]);
  return r.v;
}

// in-wave LayerNorm over 128 cols: lane holds col (n<<4)+cl, rows cq*4+j. DPP reduce.
template<bool GELU>
__device__ __forceinline__ void ln_rows(f32x4 (&acc)[8], const float* __restrict__ gvec,
                                        const float* __restrict__ bvec, int cl){
  float sm[4]={0,0,0,0}, sq[4]={0,0,0,0};
  #pragma unroll
  for (int n=0;n<8;n++)
    #pragma unroll
    for (int j=0;j<4;j++){ float x = acc[n][j]; sm[j]+=x; sq[j]+=x*x; }
  #pragma unroll
  for (int j=0;j<4;j++){
    sm[j] = dpp_sum16(sm[j]);
    sq[j] = dpp_sum16(sq[j]);
    float m = sm[j]*0.0078125f;
    float r = rsqrtf(sq[j]*0.0078125f - m*m + 1e-5f);
    sm[j]=m; sq[j]=r;
  }
  #pragma unroll
  for (int n=0;n<8;n++){
    float gg = gvec[(n<<4)+cl], be = bvec[(n<<4)+cl];
    #pragma unroll
    for (int j=0;j<4;j++){
      float y = (acc[n][j]-sm[j])*sq[j]*gg + be;
      acc[n][j] = GELU ? gelu_f(y) : y;
    }
  }
}

__device__ __forceinline__ void add_vec(f32x4 (&acc)[8], const float* __restrict__ v, int cl){
  #pragma unroll
  for (int n=0;n<8;n++){ float bv = v[(n<<4)+cl];
    #pragma unroll
    for (int j=0;j<4;j++) acc[n][j]+=bv; }
}

// wave-private group sums over rows (rows 0-5 -> s0, 6-11 -> s1), cross-cq shfl
__device__ __forceinline__ void gsum(const f32x4 (&acc)[8], float (&s0)[8], float (&s1)[8], int cq){
  #pragma unroll
  for (int n=0;n<8;n++){
    float a=0.f, b=0.f;
    #pragma unroll
    for (int j=0;j<4;j++){
      int row = (cq<<2)+j;
      float y = acc[n][j];
      a += (row<6)? y : 0.f;
      b += (row>=6 && row<12)? y : 0.f;
    }
    a += __shfl_xor(a,16); a += __shfl_xor(a,32);
    b += __shfl_xor(b,16); b += __shfl_xor(b,32);
    s0[n]=a; s1[n]=b;
  }
}

// store rows 0..11 to global f32 + wave-private LDS A tile (bf16, XOR-swizzled)
__device__ __forceinline__ void spill(const f32x4 (&acc)[8], float* __restrict__ gdst,
                                      char* Al, int cl, int cq){
  #pragma unroll
  for (int n=0;n<8;n++)
    #pragma unroll
    for (int j=0;j<4;j++){
      int R=(cq<<2)+j;
      float y=acc[n][j];
      float yo=dpp_mov<0xB1>(y);                 // xor1 partner on VALU
      if (R<12 && !(cl&1)){
        int col=(n<<4)+cl;
        *(f32x2*)(gdst + (size_t)R*128 + col) = (f32x2){y,yo};
        *(u32*)(Al + (R<<8) + ((col<<1) ^ ((R&7)<<4))) = cvtpk(y,yo);
      }
    }
}

// group sums -> wave-private S tile [2][128] bf16 (unswizzled; reads are broadcasts)
__device__ __forceinline__ void ssave(const f32x4 (&acc)[8], char* Sl, int cl, int cq){
  float s0[8], s1[8];
  gsum(acc, s0, s1, cq);
  #pragma unroll
  for (int n=0;n<8;n++){
    float a_ = dpp_mov<0xB1>(s0[n]), b_ = dpp_mov<0xB1>(s1[n]);
    if (cq==0 && !(cl&1)){
      int col=(n<<4)+cl;
      *(u32*)(Sl + (col<<1))       = cvtpk(s0[n], a_);
      *(u32*)(Sl + 256 + (col<<1)) = cvtpk(s1[n], b_);
    }
  }
}

// ---------- zero-VGPR W staging: global_load_lds, linear dest, pre-swizzled source ----------
// full slot: 32KB (512 thr x 4 x 16B)
__device__ __forceinline__ void stage_lds(u16* Wb, const u16* __restrict__ slot, int w, int lane){
  const char* g = (const char*)slot + (w<<12) + (lane<<4);
  char* l = (char*)Wb + (w<<12);
  #pragma unroll
  for (int i=0;i<4;i++)
    __builtin_amdgcn_global_load_lds(
      (const __attribute__((address_space(1))) u32*)(g + (i<<10)),
      (__attribute__((address_space(3))) u32*)(l + (i<<10)), 16, 0, 0);
}
// half slot: 16KB (512 thr x 2 x 16B), linear
__device__ __forceinline__ void stage_half(char* ldst, const char* __restrict__ gsrc, int w, int lane){
  int off = (w<<10) + (lane<<4);
  #pragma unroll
  for (int j=0;j<2;j++)
    __builtin_amdgcn_global_load_lds(
      (const __attribute__((address_space(1))) u32*)(gsrc + (j<<13) + off),
      (__attribute__((address_space(3))) u32*)(ldst + (j<<13) + off), 16, 0, 0);
}
__device__ __forceinline__ bf16x8 bfrag(const u16* Wb, int col, int kt, int cq){
  int s = (kt<<2) + cq;
  return *(const bf16x8*)((const char*)Wb + (col<<8) + ((s ^ (col&7))<<4));
}
__device__ __forceinline__ bf16x8 afrag(const char* Al, int rl, int kt, int cq){
  return *(const bf16x8*)(Al + (rl<<8) + (((kt<<6)+(cq<<4)) ^ ((rl&7)<<4)));
}

// K=128 half-GEMM: A from wave-private Al tile, B from staged Wb
template<bool INIT>
__device__ __forceinline__ void gemm_a(const u16* Wb, const char* Al, int rl, int cl, int cq,
                                       f32x4 (&acc)[8]){
  if (INIT){
    #pragma unroll
    for (int n=0;n<8;n++) acc[n]=(f32x4){0,0,0,0};
  }
  #pragma unroll
  for (int kt=0;kt<4;kt++){
    bf16x8 a = afrag(Al, rl, kt, cq);
    #pragma unroll
    for (int n=0;n<8;n++)
      acc[n] = __builtin_amdgcn_mfma_f32_16x16x32_bf16(a, bfrag(Wb,(n<<4)+cl,kt,cq), acc[n],0,0,0);
  }
}
// gemm_s col-half: output cols [n0*16, n0*16+63], B from Wbase (Wc for h0, Wb for h1)
__device__ __forceinline__ void gemm_s_h(const u16* Wbase, const char* Sl, int grp,
                                         int cl, int cq, int n0, f32x4 (&acc)[8]){
  #pragma unroll
  for (int kt=0;kt<4;kt++){
    bf16x8 a = *(const bf16x8*)(Sl + (grp<<8) + (kt<<6) + (cq<<4));
    #pragma unroll
    for (int n=0;n<4;n++)
      acc[n0+n] = __builtin_amdgcn_mfma_f32_16x16x32_bf16(a, bfrag(Wbase,((n0+n)<<4)+cl,kt,cq), acc[n0+n],0,0,0);
  }
}

// ---------- prep: 5 bf16 W^T slots, stored as the LDS IMAGE (swizzle baked into source) ----------
// u16 idx within slot for W^T[h][f]: (h<<7) + (((f>>3)^(h&7))<<3) + (f&7)
// slots: 0:W1T  16384:WxT  32768:WsvT  49152:sW1aT  65536:(u*sW1b)T
__global__ void k_prep(const float* __restrict__ W1, const float* __restrict__ chw,
                       const float* __restrict__ sW1, u16* __restrict__ WT5){
  int i = blockIdx.x*256 + threadIdx.x;          // i = f*128+h
  int f = i>>7, h = i&127;
  int dst = (h<<7) + ((((f>>3) ^ (h&7)))<<3) + (f&7);
  float w0 = chw[i], w1 = chw[16384+i], w2 = chw[32768+i];
  WT5[dst]         = f2bf(W1[i]);
  WT5[16384+dst]   = f2bf(w0 + C1_CONST*w1 + C2_CONST*w2);
  WT5[32768+dst]   = f2bf(A_CONST*w1 + A1C_CONST*w2);
  WT5[49152+dst]   = f2bf(sW1[i]);
  WT5[65536+dst]   = f2bf(U_CONST*sW1[16384+i]);
}

// ---------- fused pipeline: 8 waves/block, wave = 2 groups (12 rows), 9 barriers,
//            zero exposed DMA (Wc slack buffer holds h0 of each gemm_s table) ----------
__global__ __launch_bounds__(512, 4)
void k_all(const float* __restrict__ X_de, const u16* __restrict__ WT5,
           const float* __restrict__ b1, const float* __restrict__ ln1g, const float* __restrict__ ln1b,
           const float* __restrict__ chb, const float* __restrict__ clng, const float* __restrict__ clnb,
           const float* __restrict__ sb1, const float* __restrict__ slng, const float* __restrict__ slnb,
           const float* __restrict__ sW2, const float* __restrict__ sb2p,
           float* __restrict__ out)
{
  __shared__ __align__(16) u16  Wb[128*128];     // 32KB main staged weight (swizzled image)
  __shared__ __align__(16) u16  Wc[64*128];      // 16KB gemm_s h0 table (cols 0-63)
  __shared__ __align__(16) char lds[8][3584];    // per wave: A tile 12x256B + S tile 512B
  const int tid=threadIdx.x, w=tid>>6, lane=tid&63, cl=lane&15, cq=lane>>4;
  char* Al = lds[w];
  char* Sl = lds[w] + 3072;
  const int wid = blockIdx.x*8 + w;
  const int R0 = wid*12, g0 = wid*2;
  const int rl = (cl<12)? cl : 0;
  const int grp = (rl>=6)? 1 : 0;

  // prologue DMAs: W1T (32KB -> Wb) and WsvT-h0 (16KB -> Wc), both in flight below
  stage_lds(Wb, WT5, w, lane);
  stage_half((char*)Wc, (const char*)(WT5+32768), w, lane);

  // adj output: constant (LN over size-1 axis == aln_b -> softmax uniform). 576/block.
  {
    float* adj = out + 1048576;
    #pragma unroll
    for (int k=0;k<2;k++){ int idx = tid + (k<<9); if (idx < 576) adj[(size_t)blockIdx.x*576 + idx] = 0.16666667f; }
  }

  // stage-1 A preload
  int grow = R0 + rl;
  u32 grp6 = ((u32)grow * 43691u) >> 18;         // grow/6 (exact in range)
  int c = grow - (int)grp6*6;
  const float* xrow = X_de + (((size_t)(((int)(grp6>>7))*6 + c)<<7) + (int)(grp6&127))*128 + (cq<<3);
  f32x4 xlo0 = *(const f32x4*)(xrow);
  f32x4 xhi0 = *(const f32x4*)(xrow+4);
  f32x4 xlo1 = *(const f32x4*)(xrow+32);
  f32x4 xhi1 = *(const f32x4*)(xrow+36);
  f32x4 xlo2 = *(const f32x4*)(xrow+64);
  f32x4 xhi2 = *(const f32x4*)(xrow+68);
  f32x4 xlo3 = *(const f32x4*)(xrow+96);
  f32x4 xhi3 = *(const f32x4*)(xrow+100);
  bf16x8 af0 = pack8(xlo0,xhi0), af1 = pack8(xlo1,xhi1), af2 = pack8(xlo2,xhi2), af3 = pack8(xlo3,xhi3);
  __syncthreads();                               // b0: Wb = W1T, Wc = Wsv-h0

  // ---- stage 1: Xn = gelu(LN(X@W1 + b1)) ----
  f32x4 acc[8];
  #pragma unroll
  for (int n=0;n<8;n++) acc[n]=(f32x4){0,0,0,0};
  #pragma unroll
  for (int n=0;n<8;n++) acc[n]=__builtin_amdgcn_mfma_f32_16x16x32_bf16(af0, bfrag(Wb,(n<<4)+cl,0,cq), acc[n],0,0,0);
  #pragma unroll
  for (int n=0;n<8;n++) acc[n]=__builtin_amdgcn_mfma_f32_16x16x32_bf16(af1, bfrag(Wb,(n<<4)+cl,1,cq), acc[n],0,0,0);
  #pragma unroll
  for (int n=0;n<8;n++) acc[n]=__builtin_amdgcn_mfma_f32_16x16x32_bf16(af2, bfrag(Wb,(n<<4)+cl,2,cq), acc[n],0,0,0);
  #pragma unroll
  for (int n=0;n<8;n++) acc[n]=__builtin_amdgcn_mfma_f32_16x16x32_bf16(af3, bfrag(Wb,(n<<4)+cl,3,cq), acc[n],0,0,0);
  __syncthreads();                               // b1: all waves done reading W1T
  stage_lds(Wb, WT5+16384, w, lane);             // WxT DMA (hides under epilogue)
  add_vec(acc, b1, cl);
  ln_rows<true>(acc, ln1g, ln1b, cl);
  spill(acc, out + 1343488 + (size_t)R0*128, Al, cl, cq);   // Xn + LDS chain
  ssave(acc, Sl, cl, cq);                                   // S
  __syncthreads();                               // b2: Wb = WxT

  // ---- stage 2: g = LN(Xn@Wx + S@Wsv + chb) ----
  gemm_a<true>(Wb, Al, rl, cl, cq, acc);
  __syncthreads();                               // b3: Wx reads done (Wb.h1 free)
  stage_half((char*)Wb + 16384, (const char*)(WT5+32768) + 16384, w, lane); // Wsv-h1 -> Wb.h1
  gemm_s_h(Wc, Sl, grp, cl, cq, 0, acc);         // S@Wsv cols 0-63 (hides the DMA)
  __syncthreads();                               // b4: Wsv-h1 ready in Wb.h1
  gemm_s_h(Wb, Sl, grp, cl, cq, 4, acc);         // S@Wsv cols 64-127
  __syncthreads();                               // b5: Wb + Wc free
  stage_lds(Wb, WT5+49152, w, lane);             // sW1aT DMA (hides under epilogue)
  stage_half((char*)Wc, (const char*)(WT5+65536), w, lane); // sW1b'-h0 -> Wc
  add_vec(acc, chb, cl);
  ln_rows<false>(acc, clng, clnb, cl);
  spill(acc, out + 7634944 + (size_t)R0*128, Al, cl, cq);   // g + LDS chain
  ssave(acc, Sl, cl, cq);                                   // Sg
  __syncthreads();                               // b6: Wb = sW1aT, Wc = sW1b'-h0

  // ---- stage 3: h = gelu(LN(g@sW1a + Sg@(u*sW1b) + sb1)); att; epoch ----
  gemm_a<true>(Wb, Al, rl, cl, cq, acc);
  __syncthreads();                               // b7: sW1a reads done
  stage_half((char*)Wb + 16384, (const char*)(WT5+65536) + 16384, w, lane); // sW1b'-h1
  gemm_s_h(Wc, Sl, grp, cl, cq, 0, acc);         // Sg@(u*sW1b) cols 0-63
  __syncthreads();                               // b8: h1 ready
  gemm_s_h(Wb, Sl, grp, cl, cq, 4, acc);         // cols 64-127
  add_vec(acc, sb1, cl);
  ln_rows<true>(acc, slng, slnb, cl);

  float z0=0,z1=0,z2=0,z3=0;
  #pragma unroll
  for (int n=0;n<8;n++){
    float wv = sW2[(n<<4)+cl];
    z0 = fmaf(acc[n][0], wv, z0); z1 = fmaf(acc[n][1], wv, z1);
    z2 = fmaf(acc[n][2], wv, z2); z3 = fmaf(acc[n][3], wv, z3);
  }
  z0 = dpp_sum16(z0); z1 = dpp_sum16(z1); z2 = dpp_sum16(z2); z3 = dpp_sum16(z3);
  float s2 = sb2p[0];
  float a0 = sigmoid_f(z0+s2), a1 = sigmoid_f(z1+s2), a2 = sigmoid_f(z2+s2), a3 = sigmoid_f(z3+s2);

  // att broadcast: readlane (VALU->SGPR, exec-independent) instead of ds_bpermute __shfl.
  // src lane is compile-time per unrolled r; value is wave-uniform after the 16-lane reduce.
  float attr[12];
  #pragma unroll
  for (int r=0;r<12;r++){
    int src = (r>>2)<<4;
    float v = (r&3)==0 ? a0 : (r&3)==1 ? a1 : (r&3)==2 ? a2 : a3;
    attr[r] = __int_as_float(__builtin_amdgcn_readlane(__float_as_int(v), src));
  }
  // epoch: weighted mean over 6 node rows, g read from wave-private LDS (bf16)
  const int c2 = lane<<1;
  #pragma unroll
  for (int gi=0; gi<2; ++gi){
    float ex=0.f, ey=0.f;
    #pragma unroll
    for (int i=0;i<6;i++){
      int r = gi*6+i;
      u32 p = *(const u32*)(Al + (r<<8) + ((c2<<1) ^ ((r&7)<<4)));
      ex = fmaf(attr[r], bf2f((u16)(p&0xFFFFu)), ex);
      ey = fmaf(attr[r], bf2f((u16)(p>>16)), ey);
    }
    *(f32x2*)(out + (size_t)(g0+gi)*128 + c2) = (f32x2){ex*(1.0f/6.0f), ey*(1.0f/6.0f)};
  }
}

// ---------- launcher ----------
extern "C" void kernel_launch(void* const* d_in, const int* in_sizes, int n_in,
                              void* d_out, int out_size, void* d_ws, size_t ws_size,
                              hipStream_t stream){
  const float* X_de = (const float*)d_in[0];
  const float* W1   = (const float*)d_in[1];
  const float* b1   = (const float*)d_in[2];
  const float* ln1g = (const float*)d_in[3];
  const float* ln1b = (const float*)d_in[4];
  // d_in[5..8] (aw, ab, aln_g, aln_b) mathematically dead: LN over size-1 axis == aln_b
  const float* chw  = (const float*)d_in[9];
  const float* chb  = (const float*)d_in[10];
  const float* clng = (const float*)d_in[11];
  const float* clnb = (const float*)d_in[12];
  const float* sW1  = (const float*)d_in[13];
  const float* sb1  = (const float*)d_in[14];
  const float* slng = (const float*)d_in[15];
  const float* slnb = (const float*)d_in[16];
  const float* sW2  = (const float*)d_in[17];
  const float* sb2  = (const float*)d_in[18];

  float* out = (float*)d_out;
  u16* WT5 = (u16*)d_ws;   // 160KB: 5 x 32KB bf16 W^T slots (LDS-image layout)

  hipLaunchKernelGGL(k_prep, dim3(64),  dim3(256), 0, stream, W1, chw, sW1, WT5);
  hipLaunchKernelGGL(k_all,  dim3(512), dim3(512), 0, stream,
                     X_de, WT5, b1, ln1g, ln1b, chb, clng, clnb,
                     sb1, slng, slnb, sW2, sb2, out);
}

// Round 17
// 44.865 us; speedup vs baseline: 1.1080x; 1.0180x over previous
//
#include <hip/hip_runtime.h>
#include <math.h>

typedef unsigned short u16;
typedef unsigned int u32;
typedef __attribute__((ext_vector_type(2))) float f32x2;
typedef __attribute__((ext_vector_type(4))) float f32x4;
typedef __attribute__((ext_vector_type(8))) short bf16x8;

// adjacency-collapse constants: u = 1/(6+1e-8); s = 1+6u; c1=1/s; c2=c1^2; a=u/s; a1c=a*(1+c1)
#define U_CONST   0.16666666638888889f
#define C1_CONST  0.5000000004166667f
#define C2_CONST  0.2500000004166667f
#define A_CONST   0.08333333326388889f
#define A1C_CONST 0.12499999993055555f

__device__ __forceinline__ float bf2f(u16 u){ union{u32 i; float f;} v; v.i=((u32)u)<<16; return v.f; }
__device__ __forceinline__ u16 f2bf(float f){ union{float f; u32 i;} v; v.f=f; u32 x=v.i;
  return (u16)((x + 0x7FFFu + ((x>>16)&1u)) >> 16); }  // RNE

// packed f32 pair -> 2xbf16 (RNE), one instr
__device__ __forceinline__ u32 cvtpk(float lo, float hi){
  u32 r; asm("v_cvt_pk_bf16_f32 %0, %1, %2" : "=v"(r) : "v"(lo), "v"(hi)); return r;
}

// DPP lane exchange on VALU pipe (no LDS). 16-lane sum butterfly.
template<int C> __device__ __forceinline__ float dpp_mov(float x){
  return __int_as_float(__builtin_amdgcn_update_dpp(0, __float_as_int(x), C, 0xF, 0xF, true));
}
__device__ __forceinline__ float dpp_sum16(float v){
  v += dpp_mov<0xB1>(v);
  v += dpp_mov<0x4E>(v);
  v += dpp_mov<0x141>(v);
  v += dpp_mov<0x140>(v);
  return v;
}

// cross-half (xor32) sum on VALU: v_permlane32_swap_b32 with both operands = a gives
// vdst = lo-half broadcast, vsrc = hi-half broadcast; their sum is the xor32 reduce.
__device__ __forceinline__ float xsum32(float a){
  float ax = a, ay = a;
  asm("v_permlane32_swap_b32 %0, %1" : "+v"(ax), "+v"(ay));
  return ax + ay;
}

// tanh-form gelu: x*sigmoid(1.5957691(x+0.044715x^3)); |err vs exact erf-gelu| ~3e-4
__device__ __forceinline__ float gelu_f(float x){
  float x2 = x*x;
  float t  = x * fmaf(x2, 0.07135481283f, 1.595769122f);
  float e  = __expf(-t);
  return x * __builtin_amdgcn_rcpf(1.0f + e);
}
__device__ __forceinline__ float sigmoid_f(float z){
  return __builtin_amdgcn_rcpf(1.0f + __expf(-z));
}

__device__ __forceinline__ bf16x8 pack8(f32x4 a, f32x4 b){
  union { bf16x8 v; u32 w[4]; } r;
  r.w[0]=cvtpk(a[0],a[1]); r.w[1]=cvtpk(a[2],a[3]);
  r.w[2]=cvtpk(b[0],b[1]); r.w[3]=cvtpk(b[2],b[3]);
  return r.v;
}

// in-wave LayerNorm over 128 cols: lane holds col (n<<4)+cl, rows cq*4+j. DPP reduce.
template<bool GELU>
__device__ __forceinline__ void ln_rows(f32x4 (&acc)[8], const float* __restrict__ gvec,
                                        const float* __restrict__ bvec, int cl){
  float sm[4]={0,0,0,0}, sq[4]={0,0,0,0};
  #pragma unroll
  for (int n=0;n<8;n++)
    #pragma unroll
    for (int j=0;j<4;j++){ float x = acc[n][j]; sm[j]+=x; sq[j]+=x*x; }
  #pragma unroll
  for (int j=0;j<4;j++){
    sm[j] = dpp_sum16(sm[j]);
    sq[j] = dpp_sum16(sq[j]);
    float m = sm[j]*0.0078125f;
    float r = rsqrtf(sq[j]*0.0078125f - m*m + 1e-5f);
    sm[j]=m; sq[j]=r;
  }
  #pragma unroll
  for (int n=0;n<8;n++){
    float gg = gvec[(n<<4)+cl], be = bvec[(n<<4)+cl];
    #pragma unroll
    for (int j=0;j<4;j++){
      float y = (acc[n][j]-sm[j])*sq[j]*gg + be;
      acc[n][j] = GELU ? gelu_f(y) : y;
    }
  }
}

__device__ __forceinline__ void add_vec(f32x4 (&acc)[8], const float* __restrict__ v, int cl){
  #pragma unroll
  for (int n=0;n<8;n++){ float bv = v[(n<<4)+cl];
    #pragma unroll
    for (int j=0;j<4;j++) acc[n][j]+=bv; }
}

// wave-private group sums over rows (rows 0-5 -> s0, 6-11 -> s1):
// xor16 via shfl (LDS swizzle), xor32 via permlane32_swap (VALU).
__device__ __forceinline__ void gsum(const f32x4 (&acc)[8], float (&s0)[8], float (&s1)[8], int cq){
  #pragma unroll
  for (int n=0;n<8;n++){
    float a=0.f, b=0.f;
    #pragma unroll
    for (int j=0;j<4;j++){
      int row = (cq<<2)+j;
      float y = acc[n][j];
      a += (row<6)? y : 0.f;
      b += (row>=6 && row<12)? y : 0.f;
    }
    a += __shfl_xor(a,16);
    b += __shfl_xor(b,16);
    s0[n] = xsum32(a);
    s1[n] = xsum32(b);
  }
}

// store rows 0..11 to global f32 + wave-private LDS A tile (bf16, XOR-swizzled)
__device__ __forceinline__ void spill(const f32x4 (&acc)[8], float* __restrict__ gdst,
                                      char* Al, int cl, int cq){
  #pragma unroll
  for (int n=0;n<8;n++)
    #pragma unroll
    for (int j=0;j<4;j++){
      int R=(cq<<2)+j;
      float y=acc[n][j];
      float yo=dpp_mov<0xB1>(y);                 // xor1 partner on VALU
      if (R<12 && !(cl&1)){
        int col=(n<<4)+cl;
        *(f32x2*)(gdst + (size_t)R*128 + col) = (f32x2){y,yo};
        *(u32*)(Al + (R<<8) + ((col<<1) ^ ((R&7)<<4))) = cvtpk(y,yo);
      }
    }
}

// group sums -> wave-private S tile [2][128] bf16 (unswizzled; reads are broadcasts)
__device__ __forceinline__ void ssave(const f32x4 (&acc)[8], char* Sl, int cl, int cq){
  float s0[8], s1[8];
  gsum(acc, s0, s1, cq);
  #pragma unroll
  for (int n=0;n<8;n++){
    float a_ = dpp_mov<0xB1>(s0[n]), b_ = dpp_mov<0xB1>(s1[n]);
    if (cq==0 && !(cl&1)){
      int col=(n<<4)+cl;
      *(u32*)(Sl + (col<<1))       = cvtpk(s0[n], a_);
      *(u32*)(Sl + 256 + (col<<1)) = cvtpk(s1[n], b_);
    }
  }
}

// ---------- zero-VGPR W staging: global_load_lds, linear dest, pre-swizzled source ----------
// full slot: 32KB (512 thr x 4 x 16B)
__device__ __forceinline__ void stage_lds(u16* Wb, const u16* __restrict__ slot, int w, int lane){
  const char* g = (const char*)slot + (w<<12) + (lane<<4);
  char* l = (char*)Wb + (w<<12);
  #pragma unroll
  for (int i=0;i<4;i++)
    __builtin_amdgcn_global_load_lds(
      (const __attribute__((address_space(1))) u32*)(g + (i<<10)),
      (__attribute__((address_space(3))) u32*)(l + (i<<10)), 16, 0, 0);
}
// half slot: 16KB (512 thr x 2 x 16B), linear
__device__ __forceinline__ void stage_half(char* ldst, const char* __restrict__ gsrc, int w, int lane){
  int off = (w<<10) + (lane<<4);
  #pragma unroll
  for (int j=0;j<2;j++)
    __builtin_amdgcn_global_load_lds(
      (const __attribute__((address_space(1))) u32*)(gsrc + (j<<13) + off),
      (__attribute__((address_space(3))) u32*)(ldst + (j<<13) + off), 16, 0, 0);
}
__device__ __forceinline__ bf16x8 bfrag(const u16* Wb, int col, int kt, int cq){
  int s = (kt<<2) + cq;
  return *(const bf16x8*)((const char*)Wb + (col<<8) + ((s ^ (col&7))<<4));
}
__device__ __forceinline__ bf16x8 afrag(const char* Al, int rl, int kt, int cq){
  return *(const bf16x8*)(Al + (rl<<8) + (((kt<<6)+(cq<<4)) ^ ((rl&7)<<4)));
}

// K=128 half-GEMM: A from wave-private Al tile, B from staged Wb
template<bool INIT>
__device__ __forceinline__ void gemm_a(const u16* Wb, const char* Al, int rl, int cl, int cq,
                                       f32x4 (&acc)[8]){
  if (INIT){
    #pragma unroll
    for (int n=0;n<8;n++) acc[n]=(f32x4){0,0,0,0};
  }
  #pragma unroll
  for (int kt=0;kt<4;kt++){
    bf16x8 a = afrag(Al, rl, kt, cq);
    #pragma unroll
    for (int n=0;n<8;n++)
      acc[n] = __builtin_amdgcn_mfma_f32_16x16x32_bf16(a, bfrag(Wb,(n<<4)+cl,kt,cq), acc[n],0,0,0);
  }
}
// gemm_s col-half: output cols [n0*16, n0*16+63], B from Wbase (Wc for h0, Wb for h1)
__device__ __forceinline__ void gemm_s_h(const u16* Wbase, const char* Sl, int grp,
                                         int cl, int cq, int n0, f32x4 (&acc)[8]){
  #pragma unroll
  for (int kt=0;kt<4;kt++){
    bf16x8 a = *(const bf16x8*)(Sl + (grp<<8) + (kt<<6) + (cq<<4));
    #pragma unroll
    for (int n=0;n<4;n++)
      acc[n0+n] = __builtin_amdgcn_mfma_f32_16x16x32_bf16(a, bfrag(Wbase,((n0+n)<<4)+cl,kt,cq), acc[n0+n],0,0,0);
  }
}

// ---------- prep: 5 bf16 W^T slots (LDS-image layout) + adj constant fill ----------
// u16 idx within slot for W^T[h][f]: (h<<7) + (((f>>3)^(h&7))<<3) + (f&7)
// slots: 0:W1T  16384:WxT  32768:WsvT  49152:sW1aT  65536:(u*sW1b)T
// grid 1152x256 = 294912 = adj element count; blocks < 64 also do weight prep.
__global__ void k_prep(const float* __restrict__ W1, const float* __restrict__ chw,
                       const float* __restrict__ sW1, u16* __restrict__ WT5,
                       float* __restrict__ adj){
  int i = blockIdx.x*256 + threadIdx.x;
  adj[i] = 0.16666667f;                          // softmax(const) = 1/(6+1e-8)
  if (i < 16384){                                // i = f*128+h
    int f = i>>7, h = i&127;
    int dst = (h<<7) + ((((f>>3) ^ (h&7)))<<3) + (f&7);
    float w0 = chw[i], w1 = chw[16384+i], w2 = chw[32768+i];
    WT5[dst]         = f2bf(W1[i]);
    WT5[16384+dst]   = f2bf(w0 + C1_CONST*w1 + C2_CONST*w2);
    WT5[32768+dst]   = f2bf(A_CONST*w1 + A1C_CONST*w2);
    WT5[49152+dst]   = f2bf(sW1[i]);
    WT5[65536+dst]   = f2bf(U_CONST*sW1[16384+i]);
  }
}

// ---------- fused pipeline: 8 waves/block, wave = 2 groups (12 rows), 9 barriers,
//            zero exposed DMA (Wc slack buffer holds h0 of each gemm_s table) ----------
__global__ __launch_bounds__(512, 4)
void k_all(const float* __restrict__ X_de, const u16* __restrict__ WT5,
           const float* __restrict__ b1, const float* __restrict__ ln1g, const float* __restrict__ ln1b,
           const float* __restrict__ chb, const float* __restrict__ clng, const float* __restrict__ clnb,
           const float* __restrict__ sb1, const float* __restrict__ slng, const float* __restrict__ slnb,
           const float* __restrict__ sW2, const float* __restrict__ sb2p,
           float* __restrict__ out)
{
  __shared__ __align__(16) u16  Wb[128*128];     // 32KB main staged weight (swizzled image)
  __shared__ __align__(16) u16  Wc[64*128];      // 16KB gemm_s h0 table (cols 0-63)
  __shared__ __align__(16) char lds[8][3584];    // per wave: A tile 12x256B + S tile 512B
  const int tid=threadIdx.x, w=tid>>6, lane=tid&63, cl=lane&15, cq=lane>>4;
  char* Al = lds[w];
  char* Sl = lds[w] + 3072;
  const int wid = blockIdx.x*8 + w;
  const int R0 = wid*12, g0 = wid*2;
  const int rl = (cl<12)? cl : 0;
  const int grp = (rl>=6)? 1 : 0;

  // prologue DMAs: W1T (32KB -> Wb) and WsvT-h0 (16KB -> Wc), both in flight below
  stage_lds(Wb, WT5, w, lane);
  stage_half((char*)Wc, (const char*)(WT5+32768), w, lane);

  // stage-1 A preload
  int grow = R0 + rl;
  u32 grp6 = ((u32)grow * 43691u) >> 18;         // grow/6 (exact in range)
  int c = grow - (int)grp6*6;
  const float* xrow = X_de + (((size_t)(((int)(grp6>>7))*6 + c)<<7) + (int)(grp6&127))*128 + (cq<<3);
  f32x4 xlo0 = *(const f32x4*)(xrow);
  f32x4 xhi0 = *(const f32x4*)(xrow+4);
  f32x4 xlo1 = *(const f32x4*)(xrow+32);
  f32x4 xhi1 = *(const f32x4*)(xrow+36);
  f32x4 xlo2 = *(const f32x4*)(xrow+64);
  f32x4 xhi2 = *(const f32x4*)(xrow+68);
  f32x4 xlo3 = *(const f32x4*)(xrow+96);
  f32x4 xhi3 = *(const f32x4*)(xrow+100);
  bf16x8 af0 = pack8(xlo0,xhi0), af1 = pack8(xlo1,xhi1), af2 = pack8(xlo2,xhi2), af3 = pack8(xlo3,xhi3);
  __syncthreads();                               // b0: Wb = W1T, Wc = Wsv-h0

  // ---- stage 1: Xn = gelu(LN(X@W1 + b1)) ----
  f32x4 acc[8];
  #pragma unroll
  for (int n=0;n<8;n++) acc[n]=(f32x4){0,0,0,0};
  #pragma unroll
  for (int n=0;n<8;n++) acc[n]=__builtin_amdgcn_mfma_f32_16x16x32_bf16(af0, bfrag(Wb,(n<<4)+cl,0,cq), acc[n],0,0,0);
  #pragma unroll
  for (int n=0;n<8;n++) acc[n]=__builtin_amdgcn_mfma_f32_16x16x32_bf16(af1, bfrag(Wb,(n<<4)+cl,1,cq), acc[n],0,0,0);
  #pragma unroll
  for (int n=0;n<8;n++) acc[n]=__builtin_amdgcn_mfma_f32_16x16x32_bf16(af2, bfrag(Wb,(n<<4)+cl,2,cq), acc[n],0,0,0);
  #pragma unroll
  for (int n=0;n<8;n++) acc[n]=__builtin_amdgcn_mfma_f32_16x16x32_bf16(af3, bfrag(Wb,(n<<4)+cl,3,cq), acc[n],0,0,0);
  __syncthreads();                               // b1: all waves done reading W1T
  stage_lds(Wb, WT5+16384, w, lane);             // WxT DMA (hides under epilogue)
  add_vec(acc, b1, cl);
  ln_rows<true>(acc, ln1g, ln1b, cl);
  spill(acc, out + 1343488 + (size_t)R0*128, Al, cl, cq);   // Xn + LDS chain
  ssave(acc, Sl, cl, cq);                                   // S
  __syncthreads();                               // b2: Wb = WxT

  // ---- stage 2: g = LN(Xn@Wx + S@Wsv + chb) ----
  gemm_a<true>(Wb, Al, rl, cl, cq, acc);
  __syncthreads();                               // b3: Wx reads done (Wb.h1 free)
  stage_half((char*)Wb + 16384, (const char*)(WT5+32768) + 16384, w, lane); // Wsv-h1 -> Wb.h1
  gemm_s_h(Wc, Sl, grp, cl, cq, 0, acc);         // S@Wsv cols 0-63 (hides the DMA)
  __syncthreads();                               // b4: Wsv-h1 ready in Wb.h1
  gemm_s_h(Wb, Sl, grp, cl, cq, 4, acc);         // S@Wsv cols 64-127
  __syncthreads();                               // b5: Wb + Wc free
  stage_lds(Wb, WT5+49152, w, lane);             // sW1aT DMA (hides under epilogue)
  stage_half((char*)Wc, (const char*)(WT5+65536), w, lane); // sW1b'-h0 -> Wc
  add_vec(acc, chb, cl);
  ln_rows<false>(acc, clng, clnb, cl);
  spill(acc, out + 7634944 + (size_t)R0*128, Al, cl, cq);   // g + LDS chain
  ssave(acc, Sl, cl, cq);                                   // Sg
  __syncthreads();                               // b6: Wb = sW1aT, Wc = sW1b'-h0

  // ---- stage 3: h = gelu(LN(g@sW1a + Sg@(u*sW1b) + sb1)); att; epoch ----
  gemm_a<true>(Wb, Al, rl, cl, cq, acc);
  __syncthreads();                               // b7: sW1a reads done
  stage_half((char*)Wb + 16384, (const char*)(WT5+65536) + 16384, w, lane); // sW1b'-h1
  gemm_s_h(Wc, Sl, grp, cl, cq, 0, acc);         // Sg@(u*sW1b) cols 0-63
  __syncthreads();                               // b8: h1 ready
  gemm_s_h(Wb, Sl, grp, cl, cq, 4, acc);         // cols 64-127
  add_vec(acc, sb1, cl);
  ln_rows<true>(acc, slng, slnb, cl);

  float z0=0,z1=0,z2=0,z3=0;
  #pragma unroll
  for (int n=0;n<8;n++){
    float wv = sW2[(n<<4)+cl];
    z0 = fmaf(acc[n][0], wv, z0); z1 = fmaf(acc[n][1], wv, z1);
    z2 = fmaf(acc[n][2], wv, z2); z3 = fmaf(acc[n][3], wv, z3);
  }
  z0 = dpp_sum16(z0); z1 = dpp_sum16(z1); z2 = dpp_sum16(z2); z3 = dpp_sum16(z3);
  float s2 = sb2p[0];
  float a0 = sigmoid_f(z0+s2), a1 = sigmoid_f(z1+s2), a2 = sigmoid_f(z2+s2), a3 = sigmoid_f(z3+s2);

  // att broadcast: readlane (VALU->SGPR); src lane compile-time per unrolled r.
  float attr[12];
  #pragma unroll
  for (int r=0;r<12;r++){
    int src = (r>>2)<<4;
    float v = (r&3)==0 ? a0 : (r&3)==1 ? a1 : (r&3)==2 ? a2 : a3;
    attr[r] = __int_as_float(__builtin_amdgcn_readlane(__float_as_int(v), src));
  }
  // epoch: weighted mean over 6 node rows, g read from wave-private LDS (bf16)
  const int c2 = lane<<1;
  #pragma unroll
  for (int gi=0; gi<2; ++gi){
    float ex=0.f, ey=0.f;
    #pragma unroll
    for (int i=0;i<6;i++){
      int r = gi*6+i;
      u32 p = *(const u32*)(Al + (r<<8) + ((c2<<1) ^ ((r&7)<<4)));
      ex = fmaf(attr[r], bf2f((u16)(p&0xFFFFu)), ex);
      ey = fmaf(attr[r], bf2f((u16)(p>>16)), ey);
    }
    *(f32x2*)(out + (size_t)(g0+gi)*128 + c2) = (f32x2){ex*(1.0f/6.0f), ey*(1.0f/6.0f)};
  }
}

// ---------- launcher ----------
extern "C" void kernel_launch(void* const* d_in, const int* in_sizes, int n_in,
                              void* d_out, int out_size, void* d_ws, size_t ws_size,
                              hipStream_t stream){
  const float* X_de = (const float*)d_in[0];
  const float* W1   = (const float*)d_in[1];
  const float* b1   = (const float*)d_in[2];
  const float* ln1g = (const float*)d_in[3];
  const float* ln1b = (const float*)d_in[4];
  // d_in[5..8] (aw, ab, aln_g, aln_b) mathematically dead: LN over size-1 axis == aln_b
  const float* chw  = (const float*)d_in[9];
  const float* chb  = (const float*)d_in[10];
  const float* clng = (const float*)d_in[11];
  const float* clnb = (const float*)d_in[12];
  const float* sW1  = (const float*)d_in[13];
  const float* sb1  = (const float*)d_in[14];
  const float* slng = (const float*)d_in[15];
  const float* slnb = (const float*)d_in[16];
  const float* sW2  = (const float*)d_in[17];
  const float* sb2  = (const float*)d_in[18];

  float* out = (float*)d_out;
  u16* WT5 = (u16*)d_ws;   // 160KB: 5 x 32KB bf16 W^T slots (LDS-image layout)

  hipLaunchKernelGGL(k_prep, dim3(1152), dim3(256), 0, stream, W1, chw, sW1, WT5, out + 1048576);
  hipLaunchKernelGGL(k_all,  dim3(512),  dim3(512), 0, stream,
                     X_de, WT5, b1, ln1g, ln1b, chb, clng, clnb,
                     sb1, slng, slnb, sW2, sb2, out);
}